// Round 11
// baseline (98.537 us; speedup 1.0000x reference)
//
#include <hip/hip_runtime.h>
#include <math.h>

#define NATOMS    128
#define NSEG      7875     // segments: i in [0,124], j in [i+2,126]
#define NSEG_PAD  8192
#define OUT_PER_B 16256    // 128*127 (row-major, diagonal skipped)
#define BLOCK     512
#define TBLOCK    512
#define NCHUNK    2048     // 2016 real chunks (rows padded to x4) + 32 dead
#define CHUNK_BYTES (NCHUNK * 4)
#define WS_NEED   (CHUNK_BYTES + OUT_PER_B * 4)   // 8 KB + 65 KB = 73.2 KB

typedef float v2f __attribute__((ext_vector_type(2)));
__device__ __forceinline__ v2f mk2(float a, float b) { v2f r; r.x = a; r.y = b; return r; }

struct P3 { v2f x, y, z; };
__device__ __forceinline__ P3 psub(P3 a, P3 b) { return {a.x - b.x, a.y - b.y, a.z - b.z}; }
__device__ __forceinline__ P3 pcross(P3 a, P3 b) {
    return {a.y * b.z - a.z * b.y, a.z * b.x - a.x * b.z, a.x * b.y - a.y * b.x};
}
__device__ __forceinline__ v2f pdot(P3 a, P3 b) { return a.x * b.x + a.y * b.y + a.z * b.z; }
__device__ __forceinline__ v2f prsq(v2f q) {
    v2f r; r.x = __builtin_amdgcn_rsqf(q.x); r.y = __builtin_amdgcn_rsqf(q.y); return r;
}
__device__ __forceinline__ v2f pclip1(v2f x) {
    return __builtin_elementwise_min(__builtin_elementwise_max(x, mk2(-1.f, -1.f)),
                                     mk2(1.f, 1.f));
}

// Packed 4-term branchless asin, A&S 4.4.45 (|err| <= 6.8e-5).
__device__ __forceinline__ v2f fast_asin2(v2f x) {
    v2f a = __builtin_elementwise_abs(x);
    v2f p = mk2(-0.0187293f, -0.0187293f);
    p = p * a + mk2( 0.0742610f,  0.0742610f);
    p = p * a + mk2(-0.2121144f, -0.2121144f);
    p = p * a + mk2( 1.5707288f,  1.5707288f);
    v2f om = mk2(1.0f, 1.0f) - a;
    v2f sq; sq.x = __builtin_amdgcn_sqrtf(om.x); sq.y = __builtin_amdgcn_sqrtf(om.y);
    v2f r = mk2(1.57079632679f, 1.57079632679f) - sq * p;
    return __builtin_elementwise_copysign(r, x);
}

__device__ __forceinline__ int seg_row_base(int i) { return 125 * i - (__umul24(i, i - 1) >> 1); }

// (i,j) from linear segment id s (sqrt seed + exact fixup); s must be < NSEG.
__device__ __forceinline__ void seed_ij(int s, int &i, int &j) {
    i = (int)((251.0f - __builtin_amdgcn_sqrtf(63001.0f - 8.0f * (float)s)) * 0.5f);
    i = max(i, 0);
    i += (seg_row_base(i + 1) <= s);
    i += (seg_row_base(i + 1) <= s);
    i -= (seg_row_base(i) > s);
    i -= (seg_row_base(i) > s);
    j = s - seg_row_base(i) + i + 2;
}

__device__ __forceinline__ P3 pack3(const float4 &a, const float4 &b) {
    return { mk2(a.x, b.x), mk2(a.y, b.y), mk2(a.z, b.z) };
}

// =========== table kernel: batch-invariant maps (verified round 10) ========
// gchunk[c]: s0(13b) | j0<<13(7b) | i<<20(7b) | nv<<27(3b).
// ptab[k]:  base0(13b) | base1<<13(13b) | m0<<26(2b) | m1<<28(2b), bases
// anchored at the VALID slot of each pair (round-9 bug fixed, r10-verified).
__global__ __launch_bounds__(TBLOCK) void build_tables(
    unsigned* __restrict__ gchunk,   // u32[2048]
    unsigned* __restrict__ ptab)     // u32[16256]
{
    const int tid = blockIdx.x * TBLOCK + threadIdx.x;

    if (tid < NCHUNK) {
        int c = tid, acc = 0;
        int i = 0, j0 = 2, s0 = 0, nv = 0;
        for (int r = 0; r < 125; ++r) {
            const int len = 125 - r;            // segments in row r
            const int nch = (len + 3) >> 2;
            if (c >= acc && c < acc + nch) {
                const int off = (c - acc) << 2;
                i  = r;
                j0 = r + 2 + off;
                s0 = seg_row_base(r) + off;
                nv = min(4, len - off);
            }
            acc += nch;
        }
        gchunk[tid] = (unsigned)s0 | ((unsigned)j0 << 13)
                    | ((unsigned)i << 20) | ((unsigned)nv << 27);
    } else {
        const int k = tid - NCHUNK;
        if (k < OUT_PER_B) {
            const int r = (int)(((unsigned)k * 132105u) >> 24);   // k/127 exact
            int c = k - r * 127;
            c += (c >= r);
            const int a  = min(r, c);
            const int bb = max(r, c);

            const int am1 = a - 1;
            const int s00 = 125 * am1 - ((am1 * (am1 - 1)) >> 1) + bb - a - 2; // (a-1,b-1)
            const int s10 = s00 + 125 - a;                                     // (a,  b-1)

            const bool v00 = (a >= 1) && (a <= 125) && (bb >= a + 2);
            const bool v01 = (a >= 1) && (a <= 125) && (bb <= 126);
            const bool v10 = (a <= 124) && (bb >= a + 3);
            const bool v11 = (a <= 124) && (bb <= 126) && (bb >= a + 2);

            const int base0 = v00 ? s00 : (v01 ? s00 + 1 : 0);
            const int base1 = v10 ? s10 : (v11 ? s10 + 1 : 0);
            const unsigned m0 = ((v00 || v01) ? 1u : 0u) | ((v00 && v01) ? 2u : 0u);
            const unsigned m1 = ((v10 || v11) ? 1u : 0u) | ((v10 && v11) ? 2u : 0u);

            ptab[k] = (unsigned)base0 | ((unsigned)base1 << 13)
                    | (m0 << 26) | (m1 << 28);
        }
    }
}

// ===================== main kernel: one block per batch =====================
// Phase A: chunk-of-4 sliding window, LEAN register form. Round 10 proved
//   the algebra (n1=m_next, n3=-m_prev, q3=qm_prev) correct but its
//   precomputed 5-point ARRAYS (~112 VGPR of array state) blew the 128 cap
//   and regressed 8us. This version carries only {va, vb, mp, qp} across 4
//   unrolled steps (named scalars, peak ~90 VGPR) and loads ONE new point
//   per step: 30 ds_read_b128/thread vs round-8's 64, 3 crosses vs 4.
//   #pragma unroll 1 on the chain loop stops the compiler from interleaving
//   the two chunk-pair chains (doubling pressure); r8 precedent: sequential
//   chains allocate ~40 VGPR.
// Phase D: paired adjacent reads (ds_read2_b32) + mask validity, verified r10.
__global__ __launch_bounds__(BLOCK, 2) void writhe_main(
    const float*    __restrict__ xyz,     // (B, 128, 3)
    const unsigned* __restrict__ gchunk,  // u32[2048]
    const unsigned* __restrict__ ptab,    // u32[16256]
    float*          __restrict__ out)     // (B, 16256)
{
    __shared__ float4 sp4[NATOMS];
    __shared__ float  swr[NSEG_PAD];

    const int b = blockIdx.x;
    const int t = threadIdx.x;

    if (t < 3 * NATOMS) {
        float v = xyz[(size_t)b * (3 * NATOMS) + t];
        int a = t / 3, c = t - 3 * a;
        ((float*)&sp4[a])[c] = v;
    }
    __syncthreads();

    // ---------- Phase A: 2 packed chunk-pair chains, sequential ----------
    #pragma unroll 1
    for (int h = 0; h < 2; ++h) {
        const unsigned eA = gchunk[t + h * 1024];
        const unsigned eB = gchunk[t + h * 1024 + 512];

        const int s0A = (int)(eA & 0x1FFFu), j0A = (int)((eA >> 13) & 0x7Fu);
        const int iA  = (int)((eA >> 20) & 0x7Fu), nvA = (int)(eA >> 27);
        const int s0B = (int)(eB & 0x1FFFu), j0B = (int)((eB >> 13) & 0x7Fu);
        const int iB  = (int)((eB >> 20) & 0x7Fu), nvB = (int)(eB >> 27);

        const P3 p0 = pack3(sp4[iA],     sp4[iB]);
        const P3 p1 = pack3(sp4[iA + 1], sp4[iB + 1]);

        // window init at j0
        P3 pk = pack3(sp4[min(j0A, NATOMS - 1)], sp4[min(j0B, NATOMS - 1)]);
        P3 va = psub(pk, p0);                 // u0 of first segment
        P3 vb = psub(pk, p1);                 // u2 of first segment
        P3 mp = pcross(va, vb);               // m[s]   (n3 = -mp)
        v2f qp = pdot(mp, mp);                // qm[s]  (q3 = qp)

        #pragma unroll
        for (int s = 0; s < 4; ++s) {
            const P3 pk1 = pack3(sp4[min(j0A + s + 1, NATOMS - 1)],
                                 sp4[min(j0B + s + 1, NATOMS - 1)]);
            const P3 va1 = psub(pk1, p0);     // u1
            const P3 vb1 = psub(pk1, p1);     // u3
            const P3 m1  = pcross(va1, vb1);  // n1 = m[s+1]
            const v2f q1 = pdot(m1, m1);

            const P3 n0 = pcross(va, va1);    // u0 x u1
            const P3 n2 = pcross(vb1, vb);    // u3 x u2
            const v2f q0 = pdot(n0, n0);
            const v2f q2 = pdot(n2, n2);

            const v2f c0 = pclip1(pdot(n0, m1) * prsq(q0 * q1));
            const v2f c1 = pclip1(pdot(m1, n2) * prsq(q1 * q2));
            const v2f c2 = pclip1((-pdot(n2, mp)) * prsq(q2 * qp));
            const v2f c3 = pclip1((-pdot(mp, n0)) * prsq(qp * q0));

            const v2f sd = pdot(n2, va);      // dot(n2, u0) = -(reference sd)
            const v2f omega = fast_asin2(c0) + fast_asin2(c1)
                            + fast_asin2(c2) + fast_asin2(c3);

            v2f sgn;
            sgn.x = (sd.x > 0.f) ? -1.f : ((sd.x < 0.f) ? 1.f : 0.f);
            sgn.y = (sd.y > 0.f) ? -1.f : ((sd.y < 0.f) ? 1.f : 0.f);

            const v2f w = omega * sgn * mk2(0.15915494309189535f, 0.15915494309189535f);

            if (s < nvA) swr[s0A + s] = w.x;
            if (s < nvB) swr[s0B + s] = w.y;

            va = va1; vb = vb1; mp = m1; qp = q1;   // slide window
        }
    }
    __syncthreads();

    // ---------- Phase D: paired gathers + cndmask validity (r10) ----------
    float* ob = out + (size_t)b * OUT_PER_B;
    for (int k = t; k < OUT_PER_B; k += BLOCK) {
        const unsigned e = ptab[k];
        const int s0 = (int)(e & 0x1FFFu);
        const int s1 = (int)((e >> 13) & 0x1FFFu);
        const unsigned vm = e >> 26;             // b0:a0  b1:a1  b2:c0  b3:c1

        const float* b0 = &swr[s0];
        const float* b1 = &swr[s1];
        const float a0 = b0[0], a1 = b0[1];      // one base, +0/+4 -> ds_read2_b32
        const float c0 = b1[0], c1 = b1[1];

        const float sum = ((vm & 1u) ? a0 : 0.f) + ((vm & 2u) ? a1 : 0.f)
                        + ((vm & 4u) ? c0 : 0.f) + ((vm & 8u) ? c1 : 0.f);

        __builtin_nontemporal_store(sum, ob + k);
    }
}

// ================== fused fallback (round-6, verified) =====================
__device__ __forceinline__ v2f seg_writhe_pair(unsigned pa, unsigned pb,
                                               const float4* sp4) {
    int jA = (int)(pa & 127u), iA = (int)(pa >> 7);
    int jB = (int)(pb & 127u), iB = (int)(pb >> 7);
    float4 A0 = sp4[iA], A1 = sp4[iA + 1], A2 = sp4[jA], A3 = sp4[jA + 1];
    float4 B0 = sp4[iB], B1 = sp4[iB + 1], B2 = sp4[jB], B3 = sp4[jB + 1];
    P3 p0 = pack3(A0, B0), p1 = pack3(A1, B1), p2 = pack3(A2, B2), p3 = pack3(A3, B3);
    P3 u0 = psub(p2, p0), u1 = psub(p3, p0), u2 = psub(p2, p1), u3 = psub(p3, p1);
    P3 n0 = pcross(u0, u1), n1 = pcross(u1, u3), n2 = pcross(u3, u2), n3 = pcross(u2, u0);
    v2f q0 = pdot(n0, n0), q1 = pdot(n1, n1), q2 = pdot(n2, n2), q3 = pdot(n3, n3);
    v2f c0 = pclip1(pdot(n0, n1) * prsq(q0 * q1));
    v2f c1 = pclip1(pdot(n1, n2) * prsq(q1 * q2));
    v2f c2 = pclip1(pdot(n2, n3) * prsq(q2 * q3));
    v2f c3 = pclip1(pdot(n3, n0) * prsq(q3 * q0));
    v2f sd = pdot(n2, u0);
    v2f omega = fast_asin2(c0) + fast_asin2(c1) + fast_asin2(c2) + fast_asin2(c3);
    v2f sgn;
    sgn.x = (sd.x > 0.f) ? -1.f : ((sd.x < 0.f) ? 1.f : 0.f);
    sgn.y = (sd.y > 0.f) ? -1.f : ((sd.y < 0.f) ? 1.f : 0.f);
    return omega * sgn * mk2(0.15915494309189535f, 0.15915494309189535f);
}

__global__ __launch_bounds__(BLOCK, 2) void writhe_fused(
    const float* __restrict__ xyz, float* __restrict__ out)
{
    __shared__ float4 sp4[NATOMS];
    __shared__ float  swr[NSEG_PAD];
    __shared__ unsigned short sidx[NSEG_PAD];
    const int b = blockIdx.x;
    const int t = threadIdx.x;
    if (t < 3 * NATOMS) {
        float v = xyz[(size_t)b * (3 * NATOMS) + t];
        int a = t / 3, c = t - 3 * a;
        ((float*)&sp4[a])[c] = v;
    }
    {
        int s = t * 16;
        if (s < NSEG) {
            int i, j; seed_ij(s, i, j);
            #pragma unroll
            for (int k = 0; k < 16; ++k) {
                if (s < NSEG) sidx[s] = (unsigned short)((i << 7) | j);
                ++s; ++j;
                if (j > 126) { ++i; j = i + 2; }
            }
        }
        if (t < NSEG_PAD - NSEG) sidx[NSEG + t] = (unsigned short)((124 << 7) | 126);
    }
    __syncthreads();
    #pragma unroll
    for (int g = 0; g < 4; ++g) {
        const int sA = g * 2048 + t;
        v2f w1 = seg_writhe_pair(sidx[sA],        sidx[sA + 512],  sp4);
        v2f w2 = seg_writhe_pair(sidx[sA + 1024], sidx[sA + 1536], sp4);
        swr[sA]        = w1.x;
        swr[sA + 512]  = w1.y;
        swr[sA + 1024] = w2.x;
        swr[sA + 1536] = w2.y;
    }
    __syncthreads();
    float* ob = out + (size_t)b * OUT_PER_B;
    for (int k = t; k < OUT_PER_B; k += BLOCK) {
        const int r = (int)(((unsigned)k * 132105u) >> 24);
        int c = k - r * 127;
        c += (c >= r);
        const int a  = min(r, c);
        const int bb = max(r, c);
        const int am1 = a - 1;
        const int s00 = 125 * am1 - ((am1 * (am1 - 1)) >> 1) + bb - a - 2;
        const int s10 = s00 + 125 - a;
        const bool v00 = (a >= 1) && (a <= 125) && (bb >= a + 2);
        const bool v01 = (a >= 1) && (a <= 125) && (bb <= 126);
        const bool v10 = (a <= 124) && (bb >= a + 3);
        const bool v11 = (a <= 124) && (bb <= 126) && (bb >= a + 2);
        const int c00 = min(max(s00,     0), NSEG - 1);
        const int c01 = min(max(s00 + 1, 0), NSEG - 1);
        const int c10 = min(max(s10,     0), NSEG - 1);
        const int c11 = min(max(s10 + 1, 0), NSEG - 1);
        float sum = (v00 ? swr[c00] : 0.0f) + (v01 ? swr[c01] : 0.0f)
                  + (v10 ? swr[c10] : 0.0f) + (v11 ? swr[c11] : 0.0f);
        __builtin_nontemporal_store(sum, ob + k);
    }
}

extern "C" void kernel_launch(void* const* d_in, const int* in_sizes, int n_in,
                              void* d_out, int out_size, void* d_ws, size_t ws_size,
                              hipStream_t stream) {
    const float* xyz = (const float*)d_in[0];
    float*       out = (float*)d_out;

    int B = in_sizes[0] / (NATOMS * 3);   // 512 for the reference shapes

    if (d_ws != nullptr && ws_size >= (size_t)WS_NEED) {
        unsigned* gchunk = (unsigned*)d_ws;
        unsigned* ptab   = (unsigned*)((char*)d_ws + CHUNK_BYTES);
        const int tgrid = (NCHUNK + OUT_PER_B + TBLOCK - 1) / TBLOCK;   // 36
        build_tables<<<tgrid, TBLOCK, 0, stream>>>(gchunk, ptab);
        writhe_main<<<B, BLOCK, 0, stream>>>(xyz, gchunk, ptab, out);
    } else {
        writhe_fused<<<B, BLOCK, 0, stream>>>(xyz, out);
    }
}

// Round 12
// 88.917 us; speedup vs baseline: 1.1082x; 1.1082x over previous
//
#include <hip/hip_runtime.h>
#include <math.h>

#define NATOMS    128
#define NSEG      7875     // segments: i in [0,124], j in [i+2,126]
#define NSEG_PAD  8192
#define OUT_PER_B 16256    // 128*127 (row-major, diagonal skipped)
#define BLOCK     512
#define TBLOCK    512
#define SIDX_BYTES 16384                          // u16[8192]
#define WS_NEED   (SIDX_BYTES + OUT_PER_B * 4)    // + u32[16256] = 81,408 B

typedef float v2f __attribute__((ext_vector_type(2)));
__device__ __forceinline__ v2f mk2(float a, float b) { v2f r; r.x = a; r.y = b; return r; }

struct P3 { v2f x, y, z; };
__device__ __forceinline__ P3 psub(P3 a, P3 b) { return {a.x - b.x, a.y - b.y, a.z - b.z}; }
__device__ __forceinline__ P3 pcross(P3 a, P3 b) {
    return {a.y * b.z - a.z * b.y, a.z * b.x - a.x * b.z, a.x * b.y - a.y * b.x};
}
__device__ __forceinline__ v2f pdot(P3 a, P3 b) { return a.x * b.x + a.y * b.y + a.z * b.z; }
__device__ __forceinline__ v2f prsq(v2f q) {
    v2f r; r.x = __builtin_amdgcn_rsqf(q.x); r.y = __builtin_amdgcn_rsqf(q.y); return r;
}
__device__ __forceinline__ v2f pclip1(v2f x) {
    return __builtin_elementwise_min(__builtin_elementwise_max(x, mk2(-1.f, -1.f)),
                                     mk2(1.f, 1.f));
}

// Packed 4-term branchless asin, A&S 4.4.45 (|err| <= 6.8e-5).
__device__ __forceinline__ v2f fast_asin2(v2f x) {
    v2f a = __builtin_elementwise_abs(x);
    v2f p = mk2(-0.0187293f, -0.0187293f);
    p = p * a + mk2( 0.0742610f,  0.0742610f);
    p = p * a + mk2(-0.2121144f, -0.2121144f);
    p = p * a + mk2( 1.5707288f,  1.5707288f);
    v2f om = mk2(1.0f, 1.0f) - a;
    v2f sq; sq.x = __builtin_amdgcn_sqrtf(om.x); sq.y = __builtin_amdgcn_sqrtf(om.y);
    v2f r = mk2(1.57079632679f, 1.57079632679f) - sq * p;
    return __builtin_elementwise_copysign(r, x);
}

__device__ __forceinline__ int seg_row_base(int i) { return 125 * i - (__umul24(i, i - 1) >> 1); }

// (i,j) from linear segment id s (sqrt seed + exact fixup); s must be < NSEG.
__device__ __forceinline__ void seed_ij(int s, int &i, int &j) {
    i = (int)((251.0f - __builtin_amdgcn_sqrtf(63001.0f - 8.0f * (float)s)) * 0.5f);
    i = max(i, 0);
    i += (seg_row_base(i + 1) <= s);
    i += (seg_row_base(i + 1) <= s);
    i -= (seg_row_base(i) > s);
    i -= (seg_row_base(i) > s);
    j = s - seg_row_base(i) + i + 2;
}

__device__ __forceinline__ P3 pack3(const float4 &a, const float4 &b) {
    return { mk2(a.x, b.x), mk2(a.y, b.y), mk2(a.z, b.z) };
}

// Writhe for TWO packed segments (x-lane = pa, y-lane = pb). Coordinates from
// float4 LDS. Sign via the exact identity
//   cross(p3-p2, p1-p0) . u0 = -(u3 x u2) . u0 = -n2 . u0.
// KEPT IN THE ROUND-8 INDEPENDENT FORM: rounds 10/11 proved that any
// cross-segment sliding-window sharing (serial m/q dependency) loses more to
// ILP collapse than it saves in instruction count (88.2 -> 96.3/98.5).
__device__ __forceinline__ v2f seg_writhe_pair(unsigned pa, unsigned pb,
                                               const float4* sp4) {
    int jA = (int)(pa & 127u), iA = (int)(pa >> 7);
    int jB = (int)(pb & 127u), iB = (int)(pb >> 7);

    float4 A0 = sp4[iA], A1 = sp4[iA + 1], A2 = sp4[jA], A3 = sp4[jA + 1];
    float4 B0 = sp4[iB], B1 = sp4[iB + 1], B2 = sp4[jB], B3 = sp4[jB + 1];

    P3 p0 = pack3(A0, B0);
    P3 p1 = pack3(A1, B1);
    P3 p2 = pack3(A2, B2);
    P3 p3 = pack3(A3, B3);

    P3 u0 = psub(p2, p0);
    P3 u1 = psub(p3, p0);
    P3 u2 = psub(p2, p1);
    P3 u3 = psub(p3, p1);

    P3 n0 = pcross(u0, u1);
    P3 n1 = pcross(u1, u3);
    P3 n2 = pcross(u3, u2);
    P3 n3 = pcross(u2, u0);

    v2f q0 = pdot(n0, n0);
    v2f q1 = pdot(n1, n1);
    v2f q2 = pdot(n2, n2);
    v2f q3 = pdot(n3, n3);

    v2f c0 = pclip1(pdot(n0, n1) * prsq(q0 * q1));
    v2f c1 = pclip1(pdot(n1, n2) * prsq(q1 * q2));
    v2f c2 = pclip1(pdot(n2, n3) * prsq(q2 * q3));
    v2f c3 = pclip1(pdot(n3, n0) * prsq(q3 * q0));

    v2f sd = pdot(n2, u0);     // = -(reference sd); sign folded below
    v2f omega = fast_asin2(c0) + fast_asin2(c1) + fast_asin2(c2) + fast_asin2(c3);

    v2f sgn;
    sgn.x = (sd.x > 0.f) ? -1.f : ((sd.x < 0.f) ? 1.f : 0.f);
    sgn.y = (sd.y > 0.f) ? -1.f : ((sd.y < 0.f) ? 1.f : 0.f);

    return omega * sgn * mk2(0.15915494309189535f, 0.15915494309189535f);
}

// =========== table kernel: batch-invariant maps, once per call =============
// gseg[s]: u16 packed (i<<7)|j, padded to 8192 (round-8 verified).
// ptab[k]: base0(13b) | base1<<13(13b) | m0<<26(2b) | m1<<28(2b), each pair
// {base, base+1} read with ds_read2_b32; bases anchored at the VALID slot
// (round-9 bug fixed; round-10/11 correctness-verified twice).
__global__ __launch_bounds__(TBLOCK) void build_tables(
    unsigned short* __restrict__ gseg,   // u16[8192]
    unsigned*       __restrict__ ptab)   // u32[16256]
{
    const int tid = blockIdx.x * TBLOCK + threadIdx.x;

    if (tid < NSEG_PAD) {
        int i, j;
        if (tid < NSEG) { seed_ij(tid, i, j); }
        else            { i = 124; j = 126; }      // safe pad segment
        gseg[tid] = (unsigned short)((i << 7) | j);
    } else {
        const int k = tid - NSEG_PAD;
        if (k < OUT_PER_B) {
            const int r = (int)(((unsigned)k * 132105u) >> 24);   // k/127 exact
            int c = k - r * 127;
            c += (c >= r);
            const int a  = min(r, c);
            const int bb = max(r, c);

            const int am1 = a - 1;
            const int s00 = 125 * am1 - ((am1 * (am1 - 1)) >> 1) + bb - a - 2; // (a-1,b-1)
            const int s10 = s00 + 125 - a;                                     // (a,  b-1)

            const bool v00 = (a >= 1) && (a <= 125) && (bb >= a + 2);
            const bool v01 = (a >= 1) && (a <= 125) && (bb <= 126);
            const bool v10 = (a <= 124) && (bb >= a + 3);
            const bool v11 = (a <= 124) && (bb <= 126) && (bb >= a + 2);

            const int base0 = v00 ? s00 : (v01 ? s00 + 1 : 0);
            const int base1 = v10 ? s10 : (v11 ? s10 + 1 : 0);
            const unsigned m0 = ((v00 || v01) ? 1u : 0u) | ((v00 && v01) ? 2u : 0u);
            const unsigned m1 = ((v10 || v11) ? 1u : 0u) | ((v10 && v11) ? 2u : 0u);

            ptab[k] = (unsigned)base0 | ((unsigned)base1 << 13)
                    | (m0 << 26) | (m1 << 28);
        }
    }
}

// ===================== main kernel: one block per batch =====================
// RECOMBINATION of the two best verified halves:
//   Phase A: round-8 independent packed-pair form (16 segments/thread, full
//            ILP -- the measured-best Phase A; sliding-window variants
//            regressed via serial-dependency ILP collapse, r10/r11).
//   Phase D: round-10/11 paired encoding -- ds_read2_b32 (2 LDS ops/output
//            vs 4) + 4-byte ptab entries (halves Phase-D global traffic).
// LDS: sp4 2K + swr 32K = 34 KB. lb(512,2): r7-measured 40 VGPR, no spill.
__global__ __launch_bounds__(BLOCK, 2) void writhe_main(
    const float*          __restrict__ xyz,    // (B, 128, 3)
    const unsigned short* __restrict__ gseg,   // u16[8192]
    const unsigned*       __restrict__ ptab,   // u32[16256]
    float*                __restrict__ out)    // (B, 16256)
{
    __shared__ float4 sp4[NATOMS];
    __shared__ float  swr[NSEG_PAD];

    const int b = blockIdx.x;
    const int t = threadIdx.x;

    if (t < 3 * NATOMS) {
        float v = xyz[(size_t)b * (3 * NATOMS) + t];
        int a = t / 3, c = t - 3 * a;
        ((float*)&sp4[a])[c] = v;
    }
    __syncthreads();

    // ---------- Phase A: packed-pair writhe, 2 chains x 4 iterations ----------
    #pragma unroll
    for (int g = 0; g < 4; ++g) {
        const int sA = g * 2048 + t;           // sA..sA+1536 < 8192: unconditional
        v2f w1 = seg_writhe_pair(gseg[sA],        gseg[sA + 512],  sp4);
        v2f w2 = seg_writhe_pair(gseg[sA + 1024], gseg[sA + 1536], sp4);
        swr[sA]        = w1.x;
        swr[sA + 512]  = w1.y;
        swr[sA + 1024] = w2.x;
        swr[sA + 1536] = w2.y;
    }
    __syncthreads();

    // ---------- Phase D: paired gathers + cndmask validity ----------
    // Lane-consecutive k: stride-1 bases across lanes (conflict-free).
    float* ob = out + (size_t)b * OUT_PER_B;
    for (int k = t; k < OUT_PER_B; k += BLOCK) {
        const unsigned e = ptab[k];
        const int s0 = (int)(e & 0x1FFFu);
        const int s1 = (int)((e >> 13) & 0x1FFFu);
        const unsigned vm = e >> 26;             // b0:a0  b1:a1  b2:c0  b3:c1

        const float* b0 = &swr[s0];
        const float* b1 = &swr[s1];
        const float a0 = b0[0], a1 = b0[1];      // one base, +0/+4 -> ds_read2_b32
        const float c0 = b1[0], c1 = b1[1];

        const float sum = ((vm & 1u) ? a0 : 0.f) + ((vm & 2u) ? a1 : 0.f)
                        + ((vm & 4u) ? c0 : 0.f) + ((vm & 8u) ? c1 : 0.f);

        __builtin_nontemporal_store(sum, ob + k);
    }
}

// ================== fused fallback (round-6, verified) =====================
__global__ __launch_bounds__(BLOCK, 2) void writhe_fused(
    const float* __restrict__ xyz, float* __restrict__ out)
{
    __shared__ float4 sp4[NATOMS];
    __shared__ float  swr[NSEG_PAD];
    __shared__ unsigned short sidx[NSEG_PAD];
    const int b = blockIdx.x;
    const int t = threadIdx.x;
    if (t < 3 * NATOMS) {
        float v = xyz[(size_t)b * (3 * NATOMS) + t];
        int a = t / 3, c = t - 3 * a;
        ((float*)&sp4[a])[c] = v;
    }
    {
        int s = t * 16;
        if (s < NSEG) {
            int i, j; seed_ij(s, i, j);
            #pragma unroll
            for (int k = 0; k < 16; ++k) {
                if (s < NSEG) sidx[s] = (unsigned short)((i << 7) | j);
                ++s; ++j;
                if (j > 126) { ++i; j = i + 2; }
            }
        }
        if (t < NSEG_PAD - NSEG) sidx[NSEG + t] = (unsigned short)((124 << 7) | 126);
    }
    __syncthreads();
    #pragma unroll
    for (int g = 0; g < 4; ++g) {
        const int sA = g * 2048 + t;
        v2f w1 = seg_writhe_pair(sidx[sA],        sidx[sA + 512],  sp4);
        v2f w2 = seg_writhe_pair(sidx[sA + 1024], sidx[sA + 1536], sp4);
        swr[sA]        = w1.x;
        swr[sA + 512]  = w1.y;
        swr[sA + 1024] = w2.x;
        swr[sA + 1536] = w2.y;
    }
    __syncthreads();
    float* ob = out + (size_t)b * OUT_PER_B;
    for (int k = t; k < OUT_PER_B; k += BLOCK) {
        const int r = (int)(((unsigned)k * 132105u) >> 24);
        int c = k - r * 127;
        c += (c >= r);
        const int a  = min(r, c);
        const int bb = max(r, c);
        const int am1 = a - 1;
        const int s00 = 125 * am1 - ((am1 * (am1 - 1)) >> 1) + bb - a - 2;
        const int s10 = s00 + 125 - a;
        const bool v00 = (a >= 1) && (a <= 125) && (bb >= a + 2);
        const bool v01 = (a >= 1) && (a <= 125) && (bb <= 126);
        const bool v10 = (a <= 124) && (bb >= a + 3);
        const bool v11 = (a <= 124) && (bb <= 126) && (bb >= a + 2);
        const int c00 = min(max(s00,     0), NSEG - 1);
        const int c01 = min(max(s00 + 1, 0), NSEG - 1);
        const int c10 = min(max(s10,     0), NSEG - 1);
        const int c11 = min(max(s10 + 1, 0), NSEG - 1);
        float sum = (v00 ? swr[c00] : 0.0f) + (v01 ? swr[c01] : 0.0f)
                  + (v10 ? swr[c10] : 0.0f) + (v11 ? swr[c11] : 0.0f);
        __builtin_nontemporal_store(sum, ob + k);
    }
}

extern "C" void kernel_launch(void* const* d_in, const int* in_sizes, int n_in,
                              void* d_out, int out_size, void* d_ws, size_t ws_size,
                              hipStream_t stream) {
    const float* xyz = (const float*)d_in[0];
    float*       out = (float*)d_out;

    int B = in_sizes[0] / (NATOMS * 3);   // 512 for the reference shapes

    if (d_ws != nullptr && ws_size >= (size_t)WS_NEED) {
        unsigned short* gseg = (unsigned short*)d_ws;
        unsigned*       ptab = (unsigned*)((char*)d_ws + SIDX_BYTES);
        const int tgrid = (NSEG_PAD + OUT_PER_B + TBLOCK - 1) / TBLOCK;   // 48
        build_tables<<<tgrid, TBLOCK, 0, stream>>>(gseg, ptab);
        writhe_main<<<B, BLOCK, 0, stream>>>(xyz, gseg, ptab, out);
    } else {
        writhe_fused<<<B, BLOCK, 0, stream>>>(xyz, out);
    }
}

// Round 13
// 87.535 us; speedup vs baseline: 1.1257x; 1.0158x over previous
//
#include <hip/hip_runtime.h>
#include <math.h>

#define NATOMS    128
#define NSEG      7875     // segments: i in [0,124], j in [i+2,126]
#define NSEG_PAD  8192
#define OUT_PER_B 16256    // 128*127 (row-major, diagonal skipped)
#define BLOCK     512

typedef float v2f __attribute__((ext_vector_type(2)));
__device__ __forceinline__ v2f mk2(float a, float b) { v2f r; r.x = a; r.y = b; return r; }

struct P3 { v2f x, y, z; };
__device__ __forceinline__ P3 psub(P3 a, P3 b) { return {a.x - b.x, a.y - b.y, a.z - b.z}; }
__device__ __forceinline__ P3 pcross(P3 a, P3 b) {
    return {a.y * b.z - a.z * b.y, a.z * b.x - a.x * b.z, a.x * b.y - a.y * b.x};
}
__device__ __forceinline__ v2f pdot(P3 a, P3 b) { return a.x * b.x + a.y * b.y + a.z * b.z; }
__device__ __forceinline__ v2f prsq(v2f q) {
    v2f r; r.x = __builtin_amdgcn_rsqf(q.x); r.y = __builtin_amdgcn_rsqf(q.y); return r;
}
__device__ __forceinline__ v2f pclip1(v2f x) {
    return __builtin_elementwise_min(__builtin_elementwise_max(x, mk2(-1.f, -1.f)),
                                     mk2(1.f, 1.f));
}

// Packed 4-term branchless asin, A&S 4.4.45 (|err| <= 6.8e-5).
__device__ __forceinline__ v2f fast_asin2(v2f x) {
    v2f a = __builtin_elementwise_abs(x);
    v2f p = mk2(-0.0187293f, -0.0187293f);
    p = p * a + mk2( 0.0742610f,  0.0742610f);
    p = p * a + mk2(-0.2121144f, -0.2121144f);
    p = p * a + mk2( 1.5707288f,  1.5707288f);
    v2f om = mk2(1.0f, 1.0f) - a;
    v2f sq; sq.x = __builtin_amdgcn_sqrtf(om.x); sq.y = __builtin_amdgcn_sqrtf(om.y);
    v2f r = mk2(1.57079632679f, 1.57079632679f) - sq * p;
    return __builtin_elementwise_copysign(r, x);
}

__device__ __forceinline__ P3 pack3(const float4 &a, const float4 &b) {
    return { mk2(a.x, b.x), mk2(a.y, b.y), mk2(a.z, b.z) };
}

// ============ COMPILE-TIME TABLES (round-13: kill the 2nd launch) ===========
// Both tables are input-independent; since round 8 they were built by a
// per-call `build_tables` kernel (launch + graph gap ~3-6us). Bake them into
// .rodata via constexpr instead: zero per-launch cost, no workspace.
//
// gseg[s]: u16 packed (i<<7)|j for segment s (row-major; padded with the
// safe segment (124,126)).
struct TabS { unsigned short v[NSEG_PAD]; };
constexpr TabS make_gseg() {
    TabS t{};
    int s = 0;
    for (int i = 0; i <= 124; ++i)
        for (int j = i + 2; j <= 126; ++j)
            t.v[s++] = (unsigned short)((i << 7) | j);
    for (; s < NSEG_PAD; ++s) t.v[s] = (unsigned short)((124 << 7) | 126);
    return t;
}
__device__ constexpr TabS g_gseg = make_gseg();

// ptab[k]: base0(13b) | base1<<13(13b) | m0<<26(2b) | m1<<28(2b). Pair
// {base, base+1} read via ds_read2_b32; bases anchored at the VALID slot
// (round-9 bug fix, correctness-verified rounds 10/11/12). Built by
// iterating (a,b) pairs directly -- each pair fills BOTH mirror outputs,
// halving constexpr work (~380k steps < clang's 1M default limit).
struct TabP { unsigned v[OUT_PER_B]; };
constexpr TabP make_ptab() {
    TabP t{};
    for (int a = 0; a < 127; ++a) {
        for (int bb = a + 1; bb < 128; ++bb) {
            const int am1 = a - 1;
            const int s00 = 125 * am1 - (am1 * (am1 - 1)) / 2 + bb - a - 2; // (a-1,b-1)
            const int s10 = s00 + 125 - a;                                  // (a,  b-1)

            const bool v00 = (a >= 1) && (a <= 125) && (bb >= a + 2);
            const bool v01 = (a >= 1) && (a <= 125) && (bb <= 126);
            const bool v10 = (a <= 124) && (bb >= a + 3);
            const bool v11 = (a <= 124) && (bb <= 126) && (bb >= a + 2);

            const int base0 = v00 ? s00 : (v01 ? s00 + 1 : 0);
            const int base1 = v10 ? s10 : (v11 ? s10 + 1 : 0);
            const unsigned m0 = ((v00 || v01) ? 1u : 0u) | ((v00 && v01) ? 2u : 0u);
            const unsigned m1 = ((v10 || v11) ? 1u : 0u) | ((v10 && v11) ? 2u : 0u);

            const unsigned e = (unsigned)base0 | ((unsigned)base1 << 13)
                             | (m0 << 26) | (m1 << 28);
            t.v[127 * a + bb - 1] = e;   // (r,c) = (a,b), r < c
            t.v[127 * bb + a]     = e;   // (r,c) = (b,a), r > c
        }
    }
    return t;
}
__device__ constexpr TabP g_ptab = make_ptab();

// Writhe for TWO packed segments (x-lane = pa, y-lane = pb). Coordinates from
// float4 LDS. Sign via the exact identity
//   cross(p3-p2, p1-p0) . u0 = -(u3 x u2) . u0 = -n2 . u0.
// KEPT IN THE ROUND-8 INDEPENDENT FORM: rounds 10/11 measured that any
// cross-segment sliding-window sharing (serial m/q dependency) loses more to
// ILP collapse than it saves in instruction count (88.2 -> 96.3/98.5).
__device__ __forceinline__ v2f seg_writhe_pair(unsigned pa, unsigned pb,
                                               const float4* sp4) {
    int jA = (int)(pa & 127u), iA = (int)(pa >> 7);
    int jB = (int)(pb & 127u), iB = (int)(pb >> 7);

    float4 A0 = sp4[iA], A1 = sp4[iA + 1], A2 = sp4[jA], A3 = sp4[jA + 1];
    float4 B0 = sp4[iB], B1 = sp4[iB + 1], B2 = sp4[jB], B3 = sp4[jB + 1];

    P3 p0 = pack3(A0, B0);
    P3 p1 = pack3(A1, B1);
    P3 p2 = pack3(A2, B2);
    P3 p3 = pack3(A3, B3);

    P3 u0 = psub(p2, p0);
    P3 u1 = psub(p3, p0);
    P3 u2 = psub(p2, p1);
    P3 u3 = psub(p3, p1);

    P3 n0 = pcross(u0, u1);
    P3 n1 = pcross(u1, u3);
    P3 n2 = pcross(u3, u2);
    P3 n3 = pcross(u2, u0);

    v2f q0 = pdot(n0, n0);
    v2f q1 = pdot(n1, n1);
    v2f q2 = pdot(n2, n2);
    v2f q3 = pdot(n3, n3);

    v2f c0 = pclip1(pdot(n0, n1) * prsq(q0 * q1));
    v2f c1 = pclip1(pdot(n1, n2) * prsq(q1 * q2));
    v2f c2 = pclip1(pdot(n2, n3) * prsq(q2 * q3));
    v2f c3 = pclip1(pdot(n3, n0) * prsq(q3 * q0));

    v2f sd = pdot(n2, u0);     // = -(reference sd); sign folded below
    v2f omega = fast_asin2(c0) + fast_asin2(c1) + fast_asin2(c2) + fast_asin2(c3);

    v2f sgn;
    sgn.x = (sd.x > 0.f) ? -1.f : ((sd.x < 0.f) ? 1.f : 0.f);
    sgn.y = (sd.y > 0.f) ? -1.f : ((sd.y < 0.f) ? 1.f : 0.f);

    return omega * sgn * mk2(0.15915494309189535f, 0.15915494309189535f);
}

// ===================== main kernel: one block per batch =====================
// Identical structure to round 12 (88.9us) except tables come from .rodata
// constants instead of d_ws (same L2-resident global-load access pattern).
//   Phase A: round-8 independent packed-pair form (16 segments/thread, ILP).
//   Phase D: paired ds_read2_b32 gathers + mask validity (verified r10-r12).
// LDS: sp4 2K + swr 32K = 34 KB. lb(512,2): measured 40 VGPR (r7), no spill.
__global__ __launch_bounds__(BLOCK, 2) void writhe_main(
    const float* __restrict__ xyz,    // (B, 128, 3)
    float*       __restrict__ out)    // (B, 16256)
{
    __shared__ float4 sp4[NATOMS];
    __shared__ float  swr[NSEG_PAD];

    const int b = blockIdx.x;
    const int t = threadIdx.x;

    if (t < 3 * NATOMS) {
        float v = xyz[(size_t)b * (3 * NATOMS) + t];
        int a = t / 3, c = t - 3 * a;
        ((float*)&sp4[a])[c] = v;
    }
    __syncthreads();

    // ---------- Phase A: packed-pair writhe, 2 chains x 4 iterations ----------
    #pragma unroll
    for (int g = 0; g < 4; ++g) {
        const int sA = g * 2048 + t;           // sA..sA+1536 < 8192: unconditional
        v2f w1 = seg_writhe_pair(g_gseg.v[sA],        g_gseg.v[sA + 512],  sp4);
        v2f w2 = seg_writhe_pair(g_gseg.v[sA + 1024], g_gseg.v[sA + 1536], sp4);
        swr[sA]        = w1.x;
        swr[sA + 512]  = w1.y;
        swr[sA + 1024] = w2.x;
        swr[sA + 1536] = w2.y;
    }
    __syncthreads();

    // ---------- Phase D: paired gathers + cndmask validity ----------
    // Lane-consecutive k: stride-1 bases across lanes (conflict-free).
    float* ob = out + (size_t)b * OUT_PER_B;
    for (int k = t; k < OUT_PER_B; k += BLOCK) {
        const unsigned e = g_ptab.v[k];
        const int s0 = (int)(e & 0x1FFFu);
        const int s1 = (int)((e >> 13) & 0x1FFFu);
        const unsigned vm = e >> 26;             // b0:a0  b1:a1  b2:c0  b3:c1

        const float* b0 = &swr[s0];
        const float* b1 = &swr[s1];
        const float a0 = b0[0], a1 = b0[1];      // one base, +0/+4 -> ds_read2_b32
        const float c0 = b1[0], c1 = b1[1];

        const float sum = ((vm & 1u) ? a0 : 0.f) + ((vm & 2u) ? a1 : 0.f)
                        + ((vm & 4u) ? c0 : 0.f) + ((vm & 8u) ? c1 : 0.f);

        __builtin_nontemporal_store(sum, ob + k);
    }
}

extern "C" void kernel_launch(void* const* d_in, const int* in_sizes, int n_in,
                              void* d_out, int out_size, void* d_ws, size_t ws_size,
                              hipStream_t stream) {
    const float* xyz = (const float*)d_in[0];
    float*       out = (float*)d_out;

    int B = in_sizes[0] / (NATOMS * 3);   // 512 for the reference shapes
    writhe_main<<<B, BLOCK, 0, stream>>>(xyz, out);   // single dispatch
}

// Round 14
// 83.487 us; speedup vs baseline: 1.1803x; 1.0485x over previous
//
#include <hip/hip_runtime.h>
#include <math.h>

#define NATOMS    128
#define NSEG      7875     // segments: i in [0,124], j in [i+2,126]
#define NSEG_PAD  8192
#define OUT_PER_B 16256    // 128*127 (row-major, diagonal skipped)
#define PTAB_PAD  16384    // padded so the register prefetch never reads OOB
#define BLOCK     512
#define NPF       32       // prefetched ptab entries per thread (32*512 = 16384)

typedef float v2f __attribute__((ext_vector_type(2)));
__device__ __forceinline__ v2f mk2(float a, float b) { v2f r; r.x = a; r.y = b; return r; }

struct P3 { v2f x, y, z; };
__device__ __forceinline__ P3 psub(P3 a, P3 b) { return {a.x - b.x, a.y - b.y, a.z - b.z}; }
__device__ __forceinline__ P3 pcross(P3 a, P3 b) {
    return {a.y * b.z - a.z * b.y, a.z * b.x - a.x * b.z, a.x * b.y - a.y * b.x};
}
__device__ __forceinline__ v2f pdot(P3 a, P3 b) { return a.x * b.x + a.y * b.y + a.z * b.z; }
__device__ __forceinline__ v2f prsq(v2f q) {
    v2f r; r.x = __builtin_amdgcn_rsqf(q.x); r.y = __builtin_amdgcn_rsqf(q.y); return r;
}
__device__ __forceinline__ v2f pclip1(v2f x) {
    return __builtin_elementwise_min(__builtin_elementwise_max(x, mk2(-1.f, -1.f)),
                                     mk2(1.f, 1.f));
}

// Packed 4-term branchless asin, A&S 4.4.45 (|err| <= 6.8e-5).
__device__ __forceinline__ v2f fast_asin2(v2f x) {
    v2f a = __builtin_elementwise_abs(x);
    v2f p = mk2(-0.0187293f, -0.0187293f);
    p = p * a + mk2( 0.0742610f,  0.0742610f);
    p = p * a + mk2(-0.2121144f, -0.2121144f);
    p = p * a + mk2( 1.5707288f,  1.5707288f);
    v2f om = mk2(1.0f, 1.0f) - a;
    v2f sq; sq.x = __builtin_amdgcn_sqrtf(om.x); sq.y = __builtin_amdgcn_sqrtf(om.y);
    v2f r = mk2(1.57079632679f, 1.57079632679f) - sq * p;
    return __builtin_elementwise_copysign(r, x);
}

__device__ __forceinline__ P3 pack3(const float4 &a, const float4 &b) {
    return { mk2(a.x, b.x), mk2(a.y, b.y), mk2(a.z, b.z) };
}

// ============ COMPILE-TIME TABLES (verified round 13) =======================
// gseg[s]: u16 packed (i<<7)|j for segment s (row-major; padded with the
// safe segment (124,126)).
struct TabS { unsigned short v[NSEG_PAD]; };
constexpr TabS make_gseg() {
    TabS t{};
    int s = 0;
    for (int i = 0; i <= 124; ++i)
        for (int j = i + 2; j <= 126; ++j)
            t.v[s++] = (unsigned short)((i << 7) | j);
    for (; s < NSEG_PAD; ++s) t.v[s] = (unsigned short)((124 << 7) | 126);
    return t;
}
__device__ constexpr TabS g_gseg = make_gseg();

// ptab[k]: base0(13b) | base1<<13(13b) | m0<<26(2b) | m1<<28(2b). Pair
// {base, base+1} read via ds_read2_b32; bases anchored at the VALID slot
// (round-9 bug fix, correctness-verified rounds 10-13). Padded to 16384
// (pad entries = 0: base0=base1=0, masks=0 -> harmless) so the NPF-deep
// register prefetch never reads past the array.
struct TabP { unsigned v[PTAB_PAD]; };
constexpr TabP make_ptab() {
    TabP t{};
    for (int a = 0; a < 127; ++a) {
        for (int bb = a + 1; bb < 128; ++bb) {
            const int am1 = a - 1;
            const int s00 = 125 * am1 - (am1 * (am1 - 1)) / 2 + bb - a - 2; // (a-1,b-1)
            const int s10 = s00 + 125 - a;                                  // (a,  b-1)

            const bool v00 = (a >= 1) && (a <= 125) && (bb >= a + 2);
            const bool v01 = (a >= 1) && (a <= 125) && (bb <= 126);
            const bool v10 = (a <= 124) && (bb >= a + 3);
            const bool v11 = (a <= 124) && (bb <= 126) && (bb >= a + 2);

            const int base0 = v00 ? s00 : (v01 ? s00 + 1 : 0);
            const int base1 = v10 ? s10 : (v11 ? s10 + 1 : 0);
            const unsigned m0 = ((v00 || v01) ? 1u : 0u) | ((v00 && v01) ? 2u : 0u);
            const unsigned m1 = ((v10 || v11) ? 1u : 0u) | ((v10 && v11) ? 2u : 0u);

            const unsigned e = (unsigned)base0 | ((unsigned)base1 << 13)
                             | (m0 << 26) | (m1 << 28);
            t.v[127 * a + bb - 1] = e;   // (r,c) = (a,b), r < c
            t.v[127 * bb + a]     = e;   // (r,c) = (b,a), r > c
        }
    }
    return t;
}
__device__ constexpr TabP g_ptab = make_ptab();

// Writhe for TWO packed segments (x-lane = pa, y-lane = pb). Coordinates from
// float4 LDS. Sign via the exact identity
//   cross(p3-p2, p1-p0) . u0 = -(u3 x u2) . u0 = -n2 . u0.
// KEPT IN THE ROUND-8 INDEPENDENT FORM: rounds 10/11 measured that any
// cross-segment sliding-window sharing (serial m/q dependency) loses more to
// ILP collapse than it saves in instruction count (88.2 -> 96.3/98.5).
__device__ __forceinline__ v2f seg_writhe_pair(unsigned pa, unsigned pb,
                                               const float4* sp4) {
    int jA = (int)(pa & 127u), iA = (int)(pa >> 7);
    int jB = (int)(pb & 127u), iB = (int)(pb >> 7);

    float4 A0 = sp4[iA], A1 = sp4[iA + 1], A2 = sp4[jA], A3 = sp4[jA + 1];
    float4 B0 = sp4[iB], B1 = sp4[iB + 1], B2 = sp4[jB], B3 = sp4[jB + 1];

    P3 p0 = pack3(A0, B0);
    P3 p1 = pack3(A1, B1);
    P3 p2 = pack3(A2, B2);
    P3 p3 = pack3(A3, B3);

    P3 u0 = psub(p2, p0);
    P3 u1 = psub(p3, p0);
    P3 u2 = psub(p2, p1);
    P3 u3 = psub(p3, p1);

    P3 n0 = pcross(u0, u1);
    P3 n1 = pcross(u1, u3);
    P3 n2 = pcross(u3, u2);
    P3 n3 = pcross(u2, u0);

    v2f q0 = pdot(n0, n0);
    v2f q1 = pdot(n1, n1);
    v2f q2 = pdot(n2, n2);
    v2f q3 = pdot(n3, n3);

    v2f c0 = pclip1(pdot(n0, n1) * prsq(q0 * q1));
    v2f c1 = pclip1(pdot(n1, n2) * prsq(q1 * q2));
    v2f c2 = pclip1(pdot(n2, n3) * prsq(q2 * q3));
    v2f c3 = pclip1(pdot(n3, n0) * prsq(q3 * q0));

    v2f sd = pdot(n2, u0);     // = -(reference sd); sign folded below
    v2f omega = fast_asin2(c0) + fast_asin2(c1) + fast_asin2(c2) + fast_asin2(c3);

    v2f sgn;
    sgn.x = (sd.x > 0.f) ? -1.f : ((sd.x < 0.f) ? 1.f : 0.f);
    sgn.y = (sd.y > 0.f) ? -1.f : ((sd.y < 0.f) ? 1.f : 0.f);

    return omega * sgn * mk2(0.15915494309189535f, 0.15915494309189535f);
}

// ===================== main kernel: one block per batch =====================
// Round-14 change: the 32 ptab entries each thread needs in Phase D are
// PREFETCHED INTO REGISTERS BEFORE PHASE A (they're input-independent), so
// their L2 latency (~200cyc x pipeline depth) hides under Phase A's ~20us of
// VALU work. Post-barrier Phase D is then pure LDS + store. Cost: +32 VGPR
// held through Phase A (40 -> ~72): no occupancy impact (grid-limited to
// 4 waves/SIMD; 72 VGPR permits 7).
//   Phase A: round-8 independent packed-pair form (16 segments/thread, ILP).
//   Phase D: paired ds_read2_b32 gathers + mask validity (verified r10-r13).
// LDS: sp4 2K + swr 32K = 34 KB. lb(512,2).
__global__ __launch_bounds__(BLOCK, 2) void writhe_main(
    const float* __restrict__ xyz,    // (B, 128, 3)
    float*       __restrict__ out)    // (B, 16256)
{
    __shared__ float4 sp4[NATOMS];
    __shared__ float  swr[NSEG_PAD];

    const int b = blockIdx.x;
    const int t = threadIdx.x;

    if (t < 3 * NATOMS) {
        float v = xyz[(size_t)b * (3 * NATOMS) + t];
        int a = t / 3, c = t - 3 * a;
        ((float*)&sp4[a])[c] = v;
    }

    // ---------- ptab register prefetch (issued before Phase A) ----------
    unsigned pe[NPF];
    #pragma unroll
    for (int q = 0; q < NPF; ++q)
        pe[q] = g_ptab.v[t + q * BLOCK];     // t + 31*512 <= 16383 < PTAB_PAD

    __syncthreads();

    // ---------- Phase A: packed-pair writhe, 2 chains x 4 iterations ----------
    #pragma unroll
    for (int g = 0; g < 4; ++g) {
        const int sA = g * 2048 + t;           // sA..sA+1536 < 8192: unconditional
        v2f w1 = seg_writhe_pair(g_gseg.v[sA],        g_gseg.v[sA + 512],  sp4);
        v2f w2 = seg_writhe_pair(g_gseg.v[sA + 1024], g_gseg.v[sA + 1536], sp4);
        swr[sA]        = w1.x;
        swr[sA + 512]  = w1.y;
        swr[sA + 1024] = w2.x;
        swr[sA + 1536] = w2.y;
    }
    __syncthreads();

    // ---------- Phase D: pure-LDS paired gathers + coalesced store ----------
    // Lane-consecutive k: stride-1 bases across lanes (conflict-free).
    float* ob = out + (size_t)b * OUT_PER_B;
    #pragma unroll
    for (int q = 0; q < NPF; ++q) {
        const int k = t + q * BLOCK;
        if (q == NPF - 1 && k >= OUT_PER_B) break;   // only tail lanes exit

        const unsigned e = pe[q];
        const int s0 = (int)(e & 0x1FFFu);
        const int s1 = (int)((e >> 13) & 0x1FFFu);
        const unsigned vm = e >> 26;             // b0:a0  b1:a1  b2:c0  b3:c1

        const float* b0 = &swr[s0];
        const float* b1 = &swr[s1];
        const float a0 = b0[0], a1 = b0[1];      // one base, +0/+4 -> ds_read2_b32
        const float c0 = b1[0], c1 = b1[1];

        const float sum = ((vm & 1u) ? a0 : 0.f) + ((vm & 2u) ? a1 : 0.f)
                        + ((vm & 4u) ? c0 : 0.f) + ((vm & 8u) ? c1 : 0.f);

        __builtin_nontemporal_store(sum, ob + k);
    }
}

extern "C" void kernel_launch(void* const* d_in, const int* in_sizes, int n_in,
                              void* d_out, int out_size, void* d_ws, size_t ws_size,
                              hipStream_t stream) {
    const float* xyz = (const float*)d_in[0];
    float*       out = (float*)d_out;

    int B = in_sizes[0] / (NATOMS * 3);   // 512 for the reference shapes
    writhe_main<<<B, BLOCK, 0, stream>>>(xyz, out);   // single dispatch
}